// Round 4
// baseline (2682.645 us; speedup 1.0000x reference)
//
#include <hip/hip_runtime.h>
#include <hip/hip_cooperative_groups.h>
#include <math.h>

namespace cg = cooperative_groups;

#define B_  4
#define T_  64
#define F_  32
#define N_  512
#define H_  64

#define CN      16               // columns per block
#define NSTRIPE (N_/CN)          // 32
#define NBLK    (B_*NSTRIPE)     // 128 blocks -> 1 per CU on half the chip
#define AROWS   288
#define JW      384
#define NWAVES  9
#define NTHR    (NWAVES*64)      // 576

typedef __attribute__((ext_vector_type(8))) short short8;
typedef __attribute__((ext_vector_type(4))) float float4_;
typedef unsigned short u16;
typedef unsigned int   u32;

__device__ __host__ inline u16 f2bf(float x) {
    union { float f; u32 u; } v; v.f = x;
    u32 r = v.u + 0x7fff + ((v.u >> 16) & 1);
    return (u16)(r >> 16);
}
__device__ inline float bf2f(u16 h) {
    union { float f; u32 u; } v; v.u = ((u32)h) << 16;
    return v.f;
}

// Wc row mapping (phase-2 k index j):
//  0..95 aW taps1..3 | 96..287 bW taps1..3 | 288..319 aW tap0 | 320..383 bW tap0
__global__ void init_wc(const float* __restrict__ aW, const float* __restrict__ bW,
                        const float* __restrict__ xB, const float* __restrict__ zB,
                        u16* __restrict__ Wch, u16* __restrict__ Wcl,
                        float* __restrict__ bsum) {
    int idx = blockIdx.x * blockDim.x + threadIdx.x;
    if (idx < H_ * JW) {
        int h = idx / JW, j = idx % JW;
        float w;
        if (j < 96)       w = aW[(h*4 + (j>>5) + 1)*F_ + (j&31)];
        else if (j < 288) { int jj = j - 96; w = bW[(h*4 + (jj>>6) + 1)*H_ + (jj&63)]; }
        else if (j < 320) w = aW[(h*4)*F_ + (j - 288)];
        else              w = bW[(h*4)*H_ + (j - 320)];
        u16 hi = f2bf(w);
        Wch[idx] = hi;
        Wcl[idx] = f2bf(w - bf2f(hi));
    }
    if (idx < H_) bsum[idx] = xB[idx] + zB[idx];
}

// A (tap matrix, per b, multiplied by S_t at step t), rows:
//  0..31  x_{t-1} | 32..95 Xtap1,2(t-1) | 96..159 z_{t-2} | 160..287 Ztap1,2(t-1)
// C = A*S_t rows: 0..95 Xtap1..3(t), 96..287 Ztap1..3(t)
__global__ __launch_bounds__(NTHR, 1) void run_all(
    const float* __restrict__ x, const float* __restrict__ z0,
    const float* __restrict__ S,
    const u16* __restrict__ Wch, const u16* __restrict__ Wcl,
    const float* __restrict__ bsum, float* __restrict__ out,
    u16* __restrict__ A0h, u16* __restrict__ A0l,
    u16* __restrict__ A1h, u16* __restrict__ A1l)
{
    cg::grid_group grid = cg::this_grid();

    __shared__ __align__(16) u16 Sld[2][2][CN][40];    // [buf][hi/lo][n][k32+8pad]
    __shared__ __align__(16) u32 Cl[2][CN][196];       // [hi/lo][n][row-pair]
    __shared__ __align__(16) u16 Wl[2][H_][JW + 8];    // Wc staged once

    const int tid  = threadIdx.x;
    const int wave = tid >> 6;
    const int lane = tid & 63;
    const int c16  = lane & 15;
    const int g4   = lane >> 4;

    const int blk    = blockIdx.x;
    const int b      = (blk & 7) >> 1;                   // same-b -> 2 XCDs
    const int stripe = ((blk >> 3) << 1) | (blk & 1);
    const int n0     = stripe * CN;
    const int r0     = wave * 32;

    // one-time: Wc -> LDS
    for (int i = tid; i < H_ * JW; i += NTHR) {
        int h = i / JW, j = i % JW;
        Wl[0][h][j] = Wch[i];
        Wl[1][h][j] = Wcl[i];
    }

    auto stageS = [&](int tt, int ks, int buf) {
        if (tid < 512) {
            int n = tid & 15;
            int k = tid >> 4;            // 0..31
            const float* Sp = S + (size_t)(b*T_ + tt) * N_ * N_;
            float v = Sp[(size_t)(ks*32 + k) * N_ + n0 + n];
            u16 hi = f2bf(v);
            Sld[buf][0][n][k] = hi;
            Sld[buf][1][n][k] = f2bf(v - bf2f(hi));
        }
    };

    for (int t = 0; t < T_; ++t) {
        const int par = t & 1;
        const u16* Aph = par ? A1h : A0h;
        const u16* Apl = par ? A1l : A0l;
        u16* Anh = par ? A0h : A1h;
        u16* Anl = par ? A0l : A1l;

        // ---- stage x_t (Cl rows 288..319, A_next 0..31) and z_{t-1}
        //      (Cl rows 320..383, A_next 96..159)
        if (tid < 512) {
            const int col = tid & 15;
            const int rb  = (tid >> 4) * 3;
            #pragma unroll
            for (int j = 0; j < 3; ++j) {
                int row = rb + j;            // 0..95
                float v; int arow;
                if (row < 32) {
                    v = x[((size_t)(b*T_ + t)*F_ + row) * N_ + n0 + col];
                    arow = row;
                } else {
                    int hz = row - 32;
                    v = (t == 0)
                        ? z0[((size_t)b*H_ + hz) * N_ + n0 + col]
                        : out[((size_t)(b*T_ + (t-1))*H_ + hz) * N_ + n0 + col];
                    arow = 96 + hz;
                }
                u16 hi = f2bf(v);
                u16 lo = f2bf(v - bf2f(hi));
                ((u16*)&Cl[0][col][0])[288 + row] = hi;
                ((u16*)&Cl[1][col][0])[288 + row] = lo;
                size_t ai = ((size_t)b*AROWS + arow) * N_ + n0 + col;
                Anh[ai] = hi; Anl[ai] = lo;
            }
        }

        if (t == 0) {
            for (int i = tid; i < CN*144; i += NTHR) {
                int n = i / 144, rp = i % 144;
                Cl[0][n][rp] = 0; Cl[1][n][rp] = 0;
            }
            if (tid < 512) {
                int col = tid & 15, rb = (tid >> 4) * 6;
                #pragma unroll
                for (int j = 0; j < 6; ++j) {
                    int r = rb + j;                       // 0..191
                    int arow = (r < 64) ? 32 + r : 96 + r; // 32..95 / 160..287
                    size_t ai = ((size_t)b*AROWS + arow) * N_ + n0 + col;
                    Anh[ai] = 0; Anl[ai] = 0;
                }
            }
            stageS(1, 0, 0);   // prefetch step-1 chunk 0
        } else {
            // ============ phase 1: C[288x16] = A * S_t (bf16x3 MFMA) ============
            const u16* Ah0 = Aph + ((size_t)b*AROWS + r0 + c16) * N_;
            const u16* Al0 = Apl + ((size_t)b*AROWS + r0 + c16) * N_;

            float4_ acc[2];
            acc[0] = (float4_){0.f,0.f,0.f,0.f};
            acc[1] = (float4_){0.f,0.f,0.f,0.f};

            short8 ah[2], al[2];
            #pragma unroll
            for (int rf = 0; rf < 2; ++rf) {
                ah[rf] = *(const short8*)(Ah0 + (size_t)rf*16*N_ + g4*8);
                al[rf] = *(const short8*)(Al0 + (size_t)rf*16*N_ + g4*8);
            }
            __syncthreads();   // chunk0 (prefetched last step) + staging settled

            for (int ks = 0; ks < 16; ++ks) {
                const int buf = ks & 1;
                if (ks < 15)          stageS(t, ks + 1, buf ^ 1);
                else if (t < T_ - 1)  stageS(t + 1, 0, 0);   // buf^1 == 0 here
                short8 ahn[2], aln[2];
                if (ks < 15) {
                    #pragma unroll
                    for (int rf = 0; rf < 2; ++rf) {
                        ahn[rf] = *(const short8*)(Ah0 + (size_t)rf*16*N_ + (ks+1)*32 + g4*8);
                        aln[rf] = *(const short8*)(Al0 + (size_t)rf*16*N_ + (ks+1)*32 + g4*8);
                    }
                }
                short8 bh = *(const short8*)&Sld[buf][0][c16][g4*8];
                short8 bl = *(const short8*)&Sld[buf][1][c16][g4*8];
                #pragma unroll
                for (int rf = 0; rf < 2; ++rf) {
                    acc[rf] = __builtin_amdgcn_mfma_f32_16x16x32_bf16(ah[rf], bh, acc[rf], 0,0,0);
                    acc[rf] = __builtin_amdgcn_mfma_f32_16x16x32_bf16(ah[rf], bl, acc[rf], 0,0,0);
                    acc[rf] = __builtin_amdgcn_mfma_f32_16x16x32_bf16(al[rf], bh, acc[rf], 0,0,0);
                }
                if (ks < 15) { ah[0]=ahn[0]; ah[1]=ahn[1]; al[0]=aln[0]; al[1]=aln[1]; }
                __syncthreads();
            }

            // ---- epilogue: C -> Cl rows r0..r0+31 ; persisted taps -> A_next
            const int aoff = (wave < 2) ? 32 : (wave >= 3 && wave <= 6) ? 64 : -1;
            #pragma unroll
            for (int rf = 0; rf < 2; ++rf) {
                int crow = r0 + rf*16 + g4*4;
                int rp   = crow >> 1;
                float4_ a = acc[rf];
                u16 h0=f2bf(a.x), h1=f2bf(a.y), h2=f2bf(a.z), h3=f2bf(a.w);
                u16 l0=f2bf(a.x - bf2f(h0)), l1=f2bf(a.y - bf2f(h1));
                u16 l2=f2bf(a.z - bf2f(h2)), l3=f2bf(a.w - bf2f(h3));
                Cl[0][c16][rp]   = (u32)h0 | ((u32)h1 << 16);
                Cl[0][c16][rp+1] = (u32)h2 | ((u32)h3 << 16);
                Cl[1][c16][rp]   = (u32)l0 | ((u32)l1 << 16);
                Cl[1][c16][rp+1] = (u32)l2 | ((u32)l3 << 16);
                if (aoff > 0) {
                    size_t base = ((size_t)b*AROWS + crow + aoff) * N_ + n0 + c16;
                    Anh[base]        = h0; Anl[base]        = l0;
                    Anh[base +   N_] = h1; Anl[base +   N_] = l1;
                    Anh[base + 2*N_] = h2; Anl[base + 2*N_] = l2;
                    Anh[base + 3*N_] = h3; Anl[base + 3*N_] = l3;
                }
            }
        }
        __syncthreads();

        // ============ phase 2: z_t = tanh(Wc * taps + bias) ============
        if (wave < 4) {
            const int hf = wave;
            float4_ a2 = (float4_){0.f,0.f,0.f,0.f};
            const u16* Whp = &Wl[0][hf*16 + c16][0];
            const u16* Wlp = &Wl[1][hf*16 + c16][0];
            const u16* Th  = (const u16*)&Cl[0][c16][0];
            const u16* Tl  = (const u16*)&Cl[1][c16][0];
            #pragma unroll 4
            for (int kf = 0; kf < 12; ++kf) {
                short8 wh = *(const short8*)(Whp + kf*32 + g4*8);
                short8 wl = *(const short8*)(Wlp + kf*32 + g4*8);
                short8 th = *(const short8*)(Th  + kf*32 + g4*8);
                short8 tl = *(const short8*)(Tl  + kf*32 + g4*8);
                a2 = __builtin_amdgcn_mfma_f32_16x16x32_bf16(wh, th, a2, 0,0,0);
                a2 = __builtin_amdgcn_mfma_f32_16x16x32_bf16(wh, tl, a2, 0,0,0);
                a2 = __builtin_amdgcn_mfma_f32_16x16x32_bf16(wl, th, a2, 0,0,0);
            }
            const int h0r = hf*16 + g4*4;
            const float4 bsv = *(const float4*)(bsum + h0r);
            size_t ob = ((size_t)(b*T_ + t)*H_ + h0r) * N_ + n0 + c16;
            out[ob]        = tanhf(a2.x + bsv.x);
            out[ob +   N_] = tanhf(a2.y + bsv.y);
            out[ob + 2*N_] = tanhf(a2.z + bsv.z);
            out[ob + 3*N_] = tanhf(a2.w + bsv.w);
        }

        grid.sync();
    }
}

extern "C" void kernel_launch(void* const* d_in, const int* in_sizes, int n_in,
                              void* d_out, int out_size, void* d_ws, size_t ws_size,
                              hipStream_t stream) {
    const float* x  = (const float*)d_in[0];
    const float* z0 = (const float*)d_in[1];
    const float* S  = (const float*)d_in[2];
    const float* aW = (const float*)d_in[3];
    const float* bW = (const float*)d_in[4];
    const float* xB = (const float*)d_in[5];
    const float* zB = (const float*)d_in[6];
    float* out = (float*)d_out;

    char* p = (char*)d_ws;
    u16*   Wch  = (u16*)p;   p += (size_t)H_*JW*2;
    u16*   Wcl  = (u16*)p;   p += (size_t)H_*JW*2;
    float* bsum = (float*)p; p += 256;
    const size_t asz = (size_t)B_*AROWS*N_*2;
    u16* A0h = (u16*)p; p += asz;
    u16* A0l = (u16*)p; p += asz;
    u16* A1h = (u16*)p; p += asz;
    u16* A1l = (u16*)p; p += asz;

    init_wc<<<96, 256, 0, stream>>>(aW, bW, xB, zB, Wch, Wcl, bsum);

    void* args[] = { (void*)&x, (void*)&z0, (void*)&S, (void*)&Wch, (void*)&Wcl,
                     (void*)&bsum, (void*)&out, (void*)&A0h, (void*)&A0l,
                     (void*)&A1h, (void*)&A1l };
    hipLaunchCooperativeKernel((void*)run_all, dim3(NBLK), dim3(NTHR),
                               args, 0, stream);
}